// Round 1
// baseline (654.965 us; speedup 1.0000x reference)
//
#include <hip/hip_runtime.h>

// NNUE fused forward. One block (256 threads) per batch element.
// Phase A: gather-accumulate white/black feature rows (3080 fp32 each).
// Phase B: clipped mix + pairwise product -> f[3072] in LDS.
// Phase C: l1 = f @ (l1_w[ls*16+k] + l1f_w[k]) (16 outputs, block reduce).
// Phase D: l2 (30->32), l3 (32->1), psqt residual, write out[b].

#define DTOT 3080          // L1 + PSQT floats per ft row
#define NSLOT 770          // float4 slots per ft row

constexpr float kScale = 127.0f / 128.0f;

__device__ __forceinline__ float clip01(float x) { return fminf(fmaxf(x, 0.0f), 1.0f); }

__device__ __forceinline__ void fma4(float4& a, float s, const float4 v) {
    a.x += s * v.x; a.y += s * v.y; a.z += s * v.z; a.w += s * v.w;
}

__device__ __forceinline__ float4 mix_clip(float u, float th, const float4 w, const float4 b) {
    float4 r;
    r.x = clip01(u * w.x + th * b.x);
    r.y = clip01(u * w.y + th * b.y);
    r.z = clip01(u * w.z + th * b.z);
    r.w = clip01(u * w.w + th * b.w);
    return r;
}

__device__ __forceinline__ float4 mul_scale(const float4 a, const float4 b) {
    float4 r;
    r.x = a.x * b.x * kScale;
    r.y = a.y * b.y * kScale;
    r.z = a.z * b.z * kScale;
    r.w = a.w * b.w * kScale;
    return r;
}

__global__ __launch_bounds__(256) void nnue_fused(
    const float* __restrict__ us_arr, const float* __restrict__ them_arr,
    const int* __restrict__ wi, const float* __restrict__ wv,
    const int* __restrict__ bi, const float* __restrict__ bv,
    const int* __restrict__ pidx, const int* __restrict__ lsidx,
    const float* __restrict__ ftw, const float* __restrict__ ftb,
    const float* __restrict__ l1w, const float* __restrict__ l1b,
    const float* __restrict__ l1fw, const float* __restrict__ l1fb,
    const float* __restrict__ l2w, const float* __restrict__ l2b,
    const float* __restrict__ ow, const float* __restrict__ ob,
    float* __restrict__ out)
{
    const int b = blockIdx.x;
    const int t = threadIdx.x;

    __shared__ float4 fsh[768];      // f vector, 3072 floats
    __shared__ float psw[8], psb[8]; // psqt accumulators
    __shared__ int   sidx[64];
    __shared__ float sval[64];
    __shared__ float red[4][16];
    __shared__ float l1c[16];
    __shared__ float l1x[30];

    if (t < 32)      { sidx[t] = wi[b * 32 + t];      sval[t] = wv[b * 32 + t]; }
    else if (t < 64) { sidx[t] = bi[b * 32 + t - 32]; sval[t] = bv[b * 32 + t - 32]; }
    __syncthreads();

    // Slot ownership: every thread owns float4 slots (t, t+384).
    // Threads <128 additionally own (t+256, t+640). Threads 128,129 own the
    // psqt slots 768,769 in their "C" accumulator.
    const int sA = t;
    const int sB = t + 384;
    const int sC = (t < 128) ? (t + 256) : ((t < 130) ? (768 + (t - 128)) : -1);
    const int sD = (t < 128) ? (t + 640) : -1;

    const float4* fb4 = (const float4*)ftb;
    float4 aw0 = fb4[sA], aw1 = fb4[sB];
    float4 aw2 = (sC >= 0) ? fb4[sC] : float4{0.f, 0.f, 0.f, 0.f};
    float4 aw3 = (sD >= 0) ? fb4[sD] : float4{0.f, 0.f, 0.f, 0.f};
    float4 ab0 = aw0, ab1 = aw1, ab2 = aw2, ab3 = aw3;

    #pragma unroll 2
    for (int m = 0; m < 32; ++m) {
        const float4* rw = (const float4*)(ftw + (size_t)sidx[m]      * DTOT);
        const float4* rb = (const float4*)(ftw + (size_t)sidx[32 + m] * DTOT);
        const float vwm = sval[m], vbm = sval[32 + m];

        fma4(aw0, vwm, rw[sA]);
        fma4(aw1, vwm, rw[sB]);
        fma4(ab0, vbm, rb[sA]);
        fma4(ab1, vbm, rb[sB]);
        if (sC >= 0) { fma4(aw2, vwm, rw[sC]); fma4(ab2, vbm, rb[sC]); }
        if (sD >= 0) { fma4(aw3, vwm, rw[sD]); fma4(ab3, vbm, rb[sD]); }
    }

    const float usv = us_arr[b];
    const float thv = them_arr[b];

    // Phase B: f[j]     = clip(us*w[j]+th*b[j]) * clip(us*w[j+384]+th*b[j+384]) * s
    //          f[j+384] = clip(us*b[j]+th*w[j]) * clip(us*b[j+384]+th*w[j+384]) * s
    fsh[sA] = mul_scale(mix_clip(usv, thv, aw0, ab0), mix_clip(usv, thv, aw1, ab1));
    fsh[sB] = mul_scale(mix_clip(usv, thv, ab0, aw0), mix_clip(usv, thv, ab1, aw1));
    if (t < 128) {
        fsh[sC] = mul_scale(mix_clip(usv, thv, aw2, ab2), mix_clip(usv, thv, aw3, ab3));
        fsh[sD] = mul_scale(mix_clip(usv, thv, ab2, aw2), mix_clip(usv, thv, ab3, aw3));
    } else if (t == 128) {
        psw[0] = aw2.x; psw[1] = aw2.y; psw[2] = aw2.z; psw[3] = aw2.w;
        psb[0] = ab2.x; psb[1] = ab2.y; psb[2] = ab2.z; psb[3] = ab2.w;
    } else if (t == 129) {
        psw[4] = aw2.x; psw[5] = aw2.y; psw[6] = aw2.z; psw[7] = aw2.w;
        psb[4] = ab2.x; psb[5] = ab2.y; psb[6] = ab2.z; psb[7] = ab2.w;
    }
    __syncthreads();

    // Phase C: 16 dot products of length 3072 against l1_w[ls*16+k] + l1f_w[k]
    const int ls = lsidx[b];
    const float* wbase = l1w + (size_t)ls * 16 * 3072;
    float acc[16];
    #pragma unroll
    for (int k = 0; k < 16; ++k) acc[k] = 0.f;

    #pragma unroll
    for (int i = 0; i < 3; ++i) {
        const int col = t + 256 * i;
        const float4 fv = fsh[col];
        #pragma unroll
        for (int k = 0; k < 16; ++k) {
            const float4 w1 = ((const float4*)(wbase + (size_t)k * 3072))[col];
            const float4 w2 = ((const float4*)(l1fw + (size_t)k * 3072))[col];
            acc[k] += fv.x * (w1.x + w2.x) + fv.y * (w1.y + w2.y)
                    + fv.z * (w1.z + w2.z) + fv.w * (w1.w + w2.w);
        }
    }

    const int lane = t & 63;
    const int wave = t >> 6;
    #pragma unroll
    for (int k = 0; k < 16; ++k) {
        #pragma unroll
        for (int off = 32; off > 0; off >>= 1)
            acc[k] += __shfl_xor(acc[k], off, 64);
    }
    if (lane == 0) {
        #pragma unroll
        for (int k = 0; k < 16; ++k) red[wave][k] = acc[k];
    }
    __syncthreads();

    if (t < 16) {
        l1c[t] = red[0][t] + red[1][t] + red[2][t] + red[3][t]
               + l1b[ls * 16 + t] + l1fb[t];
    }
    __syncthreads();

    if (t < 15) {
        const float v = l1c[t];
        l1x[t]      = clip01(v * v * kScale);
        l1x[15 + t] = clip01(v);
    }
    __syncthreads();

    float partial = 0.f;
    if (t < 32) {
        const float* r2 = l2w + (size_t)(ls * 32 + t) * 30;
        float s2 = l2b[ls * 32 + t];
        #pragma unroll
        for (int i = 0; i < 30; ++i) s2 += l1x[i] * r2[i];
        partial = clip01(s2) * ow[ls * 32 + t];
    }
    #pragma unroll
    for (int off = 16; off > 0; off >>= 1)
        partial += __shfl_xor(partial, off, 64);

    if (t == 0) {
        const int pi = pidx[b];
        const float x = partial + ob[ls] + l1c[15]
                      + (psw[pi] - psb[pi]) * (usv - 0.5f);
        out[b] = x;
    }
}

extern "C" void kernel_launch(void* const* d_in, const int* in_sizes, int n_in,
                              void* d_out, int out_size, void* d_ws, size_t ws_size,
                              hipStream_t stream) {
    const float* us   = (const float*)d_in[0];
    const float* them = (const float*)d_in[1];
    const int*   wi   = (const int*)d_in[2];
    const float* wv   = (const float*)d_in[3];
    const int*   bi   = (const int*)d_in[4];
    const float* bv   = (const float*)d_in[5];
    const int*   pidx = (const int*)d_in[6];
    const int*   ls   = (const int*)d_in[7];
    const float* ftw  = (const float*)d_in[8];
    const float* ftb  = (const float*)d_in[9];
    const float* l1w  = (const float*)d_in[10];
    const float* l1b  = (const float*)d_in[11];
    const float* l1fw = (const float*)d_in[12];
    const float* l1fb = (const float*)d_in[13];
    const float* l2w  = (const float*)d_in[14];
    const float* l2b  = (const float*)d_in[15];
    const float* ow   = (const float*)d_in[16];
    const float* ob   = (const float*)d_in[17];
    float* out = (float*)d_out;

    const int B = in_sizes[0];
    nnue_fused<<<B, 256, 0, stream>>>(us, them, wi, wv, bi, bv, pidx, ls,
                                      ftw, ftb, l1w, l1b, l1fw, l1fb,
                                      l2w, l2b, ow, ob, out);
}